// Round 7
// baseline (548.182 us; speedup 1.0000x reference)
//
#include <hip/hip_runtime.h>
#include <hip/hip_bf16.h>

#define NN 100000
#define NE 640000
#define D 128

// ---- workspace layout (bytes) ----
#define OFF_COUNTS  0u                         // NN*4
#define OFF_OFFSETS 400000u                    // (NN+1)*4, padded to 400016
#define OFF_CURSOR  800016u                    // NN*4
#define OFF_PE      1201040u                   // NE*8  (int2 packed src,w)
#define WS_T2       6321040u                   // tier-2 end
#define OFF_XB      6321040u                   // NN*64*4 (packed bf16x2 rows)
#define WS_FULL     31921040u                  // tier-1 end

__device__ __forceinline__ float bflo(unsigned u) { return __uint_as_float(u << 16); }
__device__ __forceinline__ float bfhi(unsigned u) { return __uint_as_float(u & 0xffff0000u); }

// ---------------------------------------------------------------------------
// histogram of targets
// ---------------------------------------------------------------------------
__global__ __launch_bounds__(256) void k_hist(const int* __restrict__ tgt,
                                              int* __restrict__ counts) {
    int e = blockIdx.x * 256 + threadIdx.x;
    if (e < NE) atomicAdd(&counts[tgt[e]], 1);
}

// ---------------------------------------------------------------------------
// single-block exclusive scan of counts -> offsets & cursor (1024 threads)
// ---------------------------------------------------------------------------
#define SCAN_T 1024
__global__ __launch_bounds__(1024) void k_scan_all(const int* __restrict__ counts,
                                                   int* __restrict__ offsets,
                                                   int* __restrict__ cursor) {
    __shared__ int sd[SCAN_T];
    const int t = threadIdx.x;
    const int CH = (NN + SCAN_T - 1) / SCAN_T;   // 98
    const int base = t * CH;
    int s = 0;
    for (int k = 0; k < CH; ++k) { int i = base + k; if (i < NN) s += counts[i]; }
    sd[t] = s; __syncthreads();
    for (int off = 1; off < SCAN_T; off <<= 1) {   // Hillis-Steele inclusive
        int tmp = (t >= off) ? sd[t - off] : 0;
        __syncthreads();
        sd[t] += tmp;
        __syncthreads();
    }
    int run = sd[t] - s;                           // exclusive prefix
    for (int k = 0; k < CH; ++k) {
        int i = base + k;
        if (i < NN) { int c = counts[i]; offsets[i] = run; cursor[i] = run; run += c; }
    }
    if (t == 0) offsets[NN] = NE;
}

// ---------------------------------------------------------------------------
// bucket edges by target, packed (src, w) -> one 8B store per edge
// ---------------------------------------------------------------------------
__global__ __launch_bounds__(256) void k_fill(const int* __restrict__ src,
                                              const int* __restrict__ tgt,
                                              const float* __restrict__ ew,
                                              int* __restrict__ cursor,
                                              int2* __restrict__ pe) {
    int e = blockIdx.x * 256 + threadIdx.x;
    if (e < NE) {
        int t = tgt[e];
        int p = atomicAdd(&cursor[t], 1);
        pe[p] = make_int2(src[e], __float_as_int(ew[e]));
    }
}

// ---------------------------------------------------------------------------
// x (fp32) -> packed bf16x2 rows (halves gather-path bytes)
// ---------------------------------------------------------------------------
__global__ __launch_bounds__(256) void k_conv(const float* __restrict__ x,
                                              unsigned* __restrict__ xb) {
    int i = blockIdx.x * 256 + threadIdx.x;      // over NN*64 packed words
    if (i < NN * 64) {
        float2 v = ((const float2*)x)[i];
        __hip_bfloat16 b0 = __float2bfloat16(v.x);
        __hip_bfloat16 b1 = __float2bfloat16(v.y);
        unsigned u0 = *(const unsigned short*)&b0;
        unsigned u1 = *(const unsigned short*)&b1;
        xb[i] = u0 | (u1 << 16);
    }
}

// ---------------------------------------------------------------------------
// Pull aggregation, bf16 x: one wave per node, zero atomics, writes row once
// ---------------------------------------------------------------------------
__global__ __launch_bounds__(256) void k_gather_bf(const unsigned* __restrict__ xb,
                                                   const int* __restrict__ offsets,
                                                   const int2* __restrict__ pe,
                                                   float* __restrict__ out) {
    int wid = blockIdx.x * 4 + (threadIdx.x >> 6);
    int lane = threadIdx.x & 63;
    if (wid >= NN) return;
    int beg = offsets[wid], end = offsets[wid + 1];
    float a0 = 0.f, a1 = 0.f;
    int2 e = (beg < end) ? pe[beg] : make_int2(0, 0);
    for (int i = beg; i < end; ++i) {
        int2 en = (i + 1 < end) ? pe[i + 1] : make_int2(0, 0);   // prefetch
        unsigned v = xb[(size_t)e.x * 64 + lane];
        float w = __int_as_float(e.y);
        a0 = fmaf(bflo(v), w, a0);
        a1 = fmaf(bfhi(v), w, a1);
        e = en;
    }
    ((float2*)out)[(size_t)wid * 64 + lane] = make_float2(a0, a1);
}

// tier-2 variant: fp32 x directly (verified round-5 structure, pe-packed)
__global__ __launch_bounds__(256) void k_gather_f32(const float* __restrict__ x,
                                                    const int* __restrict__ offsets,
                                                    const int2* __restrict__ pe,
                                                    float* __restrict__ out) {
    int wid = blockIdx.x * 4 + (threadIdx.x >> 6);
    int lane = threadIdx.x & 63;
    if (wid >= NN) return;
    int beg = offsets[wid], end = offsets[wid + 1];
    const float2* x2 = (const float2*)x;
    float a0 = 0.f, a1 = 0.f;
    int2 e = (beg < end) ? pe[beg] : make_int2(0, 0);
    for (int i = beg; i < end; ++i) {
        int2 en = (i + 1 < end) ? pe[i + 1] : make_int2(0, 0);
        float2 v = x2[(size_t)e.x * 64 + lane];
        float w = __int_as_float(e.y);
        a0 = fmaf(v.x, w, a0);
        a1 = fmaf(v.y, w, a1);
        e = en;
    }
    ((float2*)out)[(size_t)wid * 64 + lane] = make_float2(a0, a1);
}

// ---------------------------------------------------------------------------
// In-place projection: io[n] <- io[n] @ W^T (W bf16 in LDS, 4x8 register tile)
// ---------------------------------------------------------------------------
#define PBN 64

__global__ __launch_bounds__(256) void k_project(const float* __restrict__ W,
                                                 float* __restrict__ io) {
    __shared__ __align__(16) float xs[PBN][D];            // 32 KB
    __shared__ __align__(16) __hip_bfloat16 Wb[D][D];     // 32 KB, Wb[d][f] = W[f][d]

    const int tid = threadIdx.x;

    const float4* W4 = (const float4*)W;
    for (int k = 0; k < 16; ++k) {
        int idx = k * 256 + tid;
        int f = idx & 127;
        int dq = idx >> 7;
        float4 v = W4[(size_t)f * 32 + dq];
        Wb[dq * 4 + 0][f] = __float2bfloat16(v.x);
        Wb[dq * 4 + 1][f] = __float2bfloat16(v.y);
        Wb[dq * 4 + 2][f] = __float2bfloat16(v.z);
        Wb[dq * 4 + 3][f] = __float2bfloat16(v.w);
    }

    const long nb = (long)blockIdx.x * PBN;
    const float4* io4 = (const float4*)io;
    for (int k = 0; k < 8; ++k) {
        int idx = k * 256 + tid;
        int n = idx >> 5;
        int dq = idx & 31;
        long node = nb + n;
        float4 v = (node < NN) ? io4[node * 32 + dq] : make_float4(0.f, 0.f, 0.f, 0.f);
        *(float4*)&xs[n][dq * 4] = v;
    }
    __syncthreads();

    const int fg = tid & 15;
    const int ng = tid >> 4;
    float acc[4][8];
    #pragma unroll
    for (int r = 0; r < 4; ++r)
        #pragma unroll
        for (int ff = 0; ff < 8; ++ff) acc[r][ff] = 0.f;

    for (int d = 0; d < D; d += 4) {
        float4 xv[4];
        #pragma unroll
        for (int r = 0; r < 4; ++r) xv[r] = *(const float4*)&xs[ng * 4 + r][d];
        #pragma unroll
        for (int j = 0; j < 4; ++j) {
            uint4 wv = *(const uint4*)&Wb[d + j][fg * 8];
            float wf0 = bflo(wv.x), wf1 = bfhi(wv.x);
            float wf2 = bflo(wv.y), wf3 = bfhi(wv.y);
            float wf4 = bflo(wv.z), wf5 = bfhi(wv.z);
            float wf6 = bflo(wv.w), wf7 = bfhi(wv.w);
            #pragma unroll
            for (int r = 0; r < 4; ++r) {
                float xj = ((const float*)&xv[r])[j];
                acc[r][0] = fmaf(xj, wf0, acc[r][0]);
                acc[r][1] = fmaf(xj, wf1, acc[r][1]);
                acc[r][2] = fmaf(xj, wf2, acc[r][2]);
                acc[r][3] = fmaf(xj, wf3, acc[r][3]);
                acc[r][4] = fmaf(xj, wf4, acc[r][4]);
                acc[r][5] = fmaf(xj, wf5, acc[r][5]);
                acc[r][6] = fmaf(xj, wf6, acc[r][6]);
                acc[r][7] = fmaf(xj, wf7, acc[r][7]);
            }
        }
    }

    #pragma unroll
    for (int r = 0; r < 4; ++r) {
        long node = nb + ng * 4 + r;
        if (node < NN) {
            float4* dst = (float4*)&io[node * D + fg * 8];
            dst[0] = make_float4(acc[r][0], acc[r][1], acc[r][2], acc[r][3]);
            dst[1] = make_float4(acc[r][4], acc[r][5], acc[r][6], acc[r][7]);
        }
    }
}

// ---------------------------------------------------------------------------
// tier-3 fallback: direct atomic scatter in x-space
// ---------------------------------------------------------------------------
__global__ __launch_bounds__(256) void gcn_scatter(const float* __restrict__ x,
                                                   const float* __restrict__ ew,
                                                   const int* __restrict__ src,
                                                   const int* __restrict__ tgt,
                                                   float* __restrict__ out) {
    int tid = blockIdx.x * 256 + threadIdx.x;
    int e = tid >> 5;
    int t = tid & 31;
    if (e >= NE) return;
    int s = src[e];
    int g = tgt[e];
    float w = ew[e];
    float4 xv = reinterpret_cast<const float4*>(x)[s * 32 + t];
    float* dst = out + (size_t)g * D + (t << 2);
    atomicAdd(dst + 0, xv.x * w);
    atomicAdd(dst + 1, xv.y * w);
    atomicAdd(dst + 2, xv.z * w);
    atomicAdd(dst + 3, xv.w * w);
}

extern "C" void kernel_launch(void* const* d_in, const int* in_sizes, int n_in,
                              void* d_out, int out_size, void* d_ws, size_t ws_size,
                              hipStream_t stream) {
    const float* x   = (const float*)d_in[0];
    const float* W   = (const float*)d_in[1];
    const float* ew  = (const float*)d_in[2];
    const int*   src = (const int*)d_in[3];
    const int*   tgt = (const int*)d_in[4];
    float* out = (float*)d_out;

    if (ws_size >= WS_T2) {
        char* ws = (char*)d_ws;
        int*  counts  = (int*)(ws + OFF_COUNTS);
        int*  offsets = (int*)(ws + OFF_OFFSETS);
        int*  cursor  = (int*)(ws + OFF_CURSOR);
        int2* pe      = (int2*)(ws + OFF_PE);

        hipMemsetAsync(counts, 0, (size_t)NN * sizeof(int), stream);
        k_hist<<<(NE + 255) / 256, 256, 0, stream>>>(tgt, counts);
        k_scan_all<<<1, SCAN_T, 0, stream>>>(counts, offsets, cursor);
        k_fill<<<(NE + 255) / 256, 256, 0, stream>>>(src, tgt, ew, cursor, pe);

        if (ws_size >= WS_FULL) {
            unsigned* xb = (unsigned*)(ws + OFF_XB);
            k_conv<<<(NN * 64 + 255) / 256, 256, 0, stream>>>(x, xb);
            k_gather_bf<<<(NN + 3) / 4, 256, 0, stream>>>(xb, offsets, pe, out);
        } else {
            k_gather_f32<<<(NN + 3) / 4, 256, 0, stream>>>(x, offsets, pe, out);
        }
    } else {
        hipMemsetAsync(out, 0, (size_t)out_size * sizeof(float), stream);
        gcn_scatter<<<(NE * 32 + 255) / 256, 256, 0, stream>>>(x, ew, src, tgt, out);
    }

    k_project<<<(NN + PBN - 1) / PBN, 256, 0, stream>>>(W, out);
}

// Round 8
// 294.096 us; speedup vs baseline: 1.8640x; 1.8640x over previous
//
#include <hip/hip_runtime.h>
#include <hip/hip_bf16.h>

#define NN 100000
#define NE 640000
#define D 128

#define SCAN_CHUNK 1024
#define NBLK ((NN + SCAN_CHUNK - 1) / SCAN_CHUNK)   // 98

// ---- workspace layout (bytes) ----
#define OFF_COUNTS  0u                         // NN*4
#define OFF_OFFSETS 400000u                    // (NN+1)*4, padded
#define OFF_CURSOR  800016u                    // NN*4
#define OFF_BSUM    1200016u                   // 512 B
#define OFF_BSUMEX  1200528u                   // 512 B
#define OFF_PE      1201040u                   // NE*8  (int2 packed src,w)
#define WS_T2       6321040u                   // tier-2 end
#define OFF_XB      6321040u                   // NN*64*4 (packed bf16x2 rows)
#define WS_FULL     31921040u                  // tier-1 end

__device__ __forceinline__ float bflo(unsigned u) { return __uint_as_float(u << 16); }
__device__ __forceinline__ float bfhi(unsigned u) { return __uint_as_float(u & 0xffff0000u); }

// ---------------------------------------------------------------------------
// histogram of targets
// ---------------------------------------------------------------------------
__global__ __launch_bounds__(256) void k_hist(const int* __restrict__ tgt,
                                              int* __restrict__ counts) {
    int e = blockIdx.x * 256 + threadIdx.x;
    if (e < NE) atomicAdd(&counts[tgt[e]], 1);
}

// ---------------------------------------------------------------------------
// multi-block scan (round-5 verified): partial sums -> mid scan -> final
// ---------------------------------------------------------------------------
__global__ __launch_bounds__(256) void k_scan_part(const int* __restrict__ counts,
                                                   int* __restrict__ bsum) {
    __shared__ int sd[256];
    int b = blockIdx.x, t = threadIdx.x;
    int base = b * SCAN_CHUNK + t * 4;
    int s = 0;
    #pragma unroll
    for (int k = 0; k < 4; ++k) { int i = base + k; s += (i < NN) ? counts[i] : 0; }
    sd[t] = s; __syncthreads();
    for (int off = 128; off > 0; off >>= 1) {
        if (t < off) sd[t] += sd[t + off];
        __syncthreads();
    }
    if (t == 0) bsum[b] = sd[0];
}

__global__ __launch_bounds__(128) void k_scan_mid(const int* __restrict__ bsum,
                                                  int* __restrict__ bsumex,
                                                  int* __restrict__ offsets) {
    __shared__ int sd[128];
    int t = threadIdx.x;
    int v = (t < NBLK) ? bsum[t] : 0;
    sd[t] = v; __syncthreads();
    for (int off = 1; off < 128; off <<= 1) {
        int tmp = (t >= off) ? sd[t - off] : 0;
        __syncthreads();
        sd[t] += tmp;
        __syncthreads();
    }
    if (t < NBLK) bsumex[t] = sd[t] - v;
    if (t == 0) offsets[NN] = NE;
}

__global__ __launch_bounds__(256) void k_scan_final(const int* __restrict__ counts,
                                                    const int* __restrict__ bsumex,
                                                    int* __restrict__ offsets,
                                                    int* __restrict__ cursor) {
    __shared__ int sd[256];
    int b = blockIdx.x, t = threadIdx.x;
    int base = b * SCAN_CHUNK + t * 4;
    int c[4]; int s = 0;
    #pragma unroll
    for (int k = 0; k < 4; ++k) { int i = base + k; c[k] = (i < NN) ? counts[i] : 0; s += c[k]; }
    sd[t] = s; __syncthreads();
    for (int off = 1; off < 256; off <<= 1) {
        int tmp = (t >= off) ? sd[t - off] : 0;
        __syncthreads();
        sd[t] += tmp;
        __syncthreads();
    }
    int run = sd[t] - s + bsumex[b];
    #pragma unroll
    for (int k = 0; k < 4; ++k) {
        int i = base + k;
        if (i < NN) { offsets[i] = run; cursor[i] = run; }
        run += c[k];
    }
}

// ---------------------------------------------------------------------------
// bucket edges by target, packed (src, w) -> one 8B store per edge
// ---------------------------------------------------------------------------
__global__ __launch_bounds__(256) void k_fill(const int* __restrict__ src,
                                              const int* __restrict__ tgt,
                                              const float* __restrict__ ew,
                                              int* __restrict__ cursor,
                                              int2* __restrict__ pe) {
    int e = blockIdx.x * 256 + threadIdx.x;
    if (e < NE) {
        int t = tgt[e];
        int p = atomicAdd(&cursor[t], 1);
        pe[p] = make_int2(src[e], __float_as_int(ew[e]));
    }
}

// ---------------------------------------------------------------------------
// x (fp32) -> packed bf16x2 rows (halves gather-path bytes)
// ---------------------------------------------------------------------------
__global__ __launch_bounds__(256) void k_conv(const float* __restrict__ x,
                                              unsigned* __restrict__ xb) {
    int i = blockIdx.x * 256 + threadIdx.x;      // over NN*64 packed words
    if (i < NN * 64) {
        float2 v = ((const float2*)x)[i];
        __hip_bfloat16 b0 = __float2bfloat16(v.x);
        __hip_bfloat16 b1 = __float2bfloat16(v.y);
        unsigned u0 = *(const unsigned short*)&b0;
        unsigned u1 = *(const unsigned short*)&b1;
        xb[i] = u0 | (u1 << 16);
    }
}

// ---------------------------------------------------------------------------
// Pull aggregation, bf16 x: one wave per node, zero atomics, writes row once
// ---------------------------------------------------------------------------
__global__ __launch_bounds__(256) void k_gather_bf(const unsigned* __restrict__ xb,
                                                   const int* __restrict__ offsets,
                                                   const int2* __restrict__ pe,
                                                   float* __restrict__ out) {
    int wid = blockIdx.x * 4 + (threadIdx.x >> 6);
    int lane = threadIdx.x & 63;
    if (wid >= NN) return;
    int beg = offsets[wid], end = offsets[wid + 1];
    float a0 = 0.f, a1 = 0.f;
    int2 e = (beg < end) ? pe[beg] : make_int2(0, 0);
    for (int i = beg; i < end; ++i) {
        int2 en = (i + 1 < end) ? pe[i + 1] : make_int2(0, 0);   // prefetch
        unsigned v = xb[(size_t)e.x * 64 + lane];
        float w = __int_as_float(e.y);
        a0 = fmaf(bflo(v), w, a0);
        a1 = fmaf(bfhi(v), w, a1);
        e = en;
    }
    ((float2*)out)[(size_t)wid * 64 + lane] = make_float2(a0, a1);
}

// tier-2 variant: fp32 x directly (round-5 verified structure, pe-packed)
__global__ __launch_bounds__(256) void k_gather_f32(const float* __restrict__ x,
                                                    const int* __restrict__ offsets,
                                                    const int2* __restrict__ pe,
                                                    float* __restrict__ out) {
    int wid = blockIdx.x * 4 + (threadIdx.x >> 6);
    int lane = threadIdx.x & 63;
    if (wid >= NN) return;
    int beg = offsets[wid], end = offsets[wid + 1];
    const float2* x2 = (const float2*)x;
    float a0 = 0.f, a1 = 0.f;
    int2 e = (beg < end) ? pe[beg] : make_int2(0, 0);
    for (int i = beg; i < end; ++i) {
        int2 en = (i + 1 < end) ? pe[i + 1] : make_int2(0, 0);
        float2 v = x2[(size_t)e.x * 64 + lane];
        float w = __int_as_float(e.y);
        a0 = fmaf(v.x, w, a0);
        a1 = fmaf(v.y, w, a1);
        e = en;
    }
    ((float2*)out)[(size_t)wid * 64 + lane] = make_float2(a0, a1);
}

// ---------------------------------------------------------------------------
// In-place projection: io[n] <- io[n] @ W^T (W bf16 in LDS, 4x8 register tile)
// ---------------------------------------------------------------------------
#define PBN 64

__global__ __launch_bounds__(256) void k_project(const float* __restrict__ W,
                                                 float* __restrict__ io) {
    __shared__ __align__(16) float xs[PBN][D];            // 32 KB
    __shared__ __align__(16) __hip_bfloat16 Wb[D][D];     // 32 KB, Wb[d][f] = W[f][d]

    const int tid = threadIdx.x;

    const float4* W4 = (const float4*)W;
    for (int k = 0; k < 16; ++k) {
        int idx = k * 256 + tid;
        int f = idx & 127;
        int dq = idx >> 7;
        float4 v = W4[(size_t)f * 32 + dq];
        Wb[dq * 4 + 0][f] = __float2bfloat16(v.x);
        Wb[dq * 4 + 1][f] = __float2bfloat16(v.y);
        Wb[dq * 4 + 2][f] = __float2bfloat16(v.z);
        Wb[dq * 4 + 3][f] = __float2bfloat16(v.w);
    }

    const long nb = (long)blockIdx.x * PBN;
    const float4* io4 = (const float4*)io;
    for (int k = 0; k < 8; ++k) {
        int idx = k * 256 + tid;
        int n = idx >> 5;
        int dq = idx & 31;
        long node = nb + n;
        float4 v = (node < NN) ? io4[node * 32 + dq] : make_float4(0.f, 0.f, 0.f, 0.f);
        *(float4*)&xs[n][dq * 4] = v;
    }
    __syncthreads();

    const int fg = tid & 15;
    const int ng = tid >> 4;
    float acc[4][8];
    #pragma unroll
    for (int r = 0; r < 4; ++r)
        #pragma unroll
        for (int ff = 0; ff < 8; ++ff) acc[r][ff] = 0.f;

    for (int d = 0; d < D; d += 4) {
        float4 xv[4];
        #pragma unroll
        for (int r = 0; r < 4; ++r) xv[r] = *(const float4*)&xs[ng * 4 + r][d];
        #pragma unroll
        for (int j = 0; j < 4; ++j) {
            uint4 wv = *(const uint4*)&Wb[d + j][fg * 8];
            float wf0 = bflo(wv.x), wf1 = bfhi(wv.x);
            float wf2 = bflo(wv.y), wf3 = bfhi(wv.y);
            float wf4 = bflo(wv.z), wf5 = bfhi(wv.z);
            float wf6 = bflo(wv.w), wf7 = bfhi(wv.w);
            #pragma unroll
            for (int r = 0; r < 4; ++r) {
                float xj = ((const float*)&xv[r])[j];
                acc[r][0] = fmaf(xj, wf0, acc[r][0]);
                acc[r][1] = fmaf(xj, wf1, acc[r][1]);
                acc[r][2] = fmaf(xj, wf2, acc[r][2]);
                acc[r][3] = fmaf(xj, wf3, acc[r][3]);
                acc[r][4] = fmaf(xj, wf4, acc[r][4]);
                acc[r][5] = fmaf(xj, wf5, acc[r][5]);
                acc[r][6] = fmaf(xj, wf6, acc[r][6]);
                acc[r][7] = fmaf(xj, wf7, acc[r][7]);
            }
        }
    }

    #pragma unroll
    for (int r = 0; r < 4; ++r) {
        long node = nb + ng * 4 + r;
        if (node < NN) {
            float4* dst = (float4*)&io[node * D + fg * 8];
            dst[0] = make_float4(acc[r][0], acc[r][1], acc[r][2], acc[r][3]);
            dst[1] = make_float4(acc[r][4], acc[r][5], acc[r][6], acc[r][7]);
        }
    }
}

// ---------------------------------------------------------------------------
// tier-3 fallback: direct atomic scatter in x-space
// ---------------------------------------------------------------------------
__global__ __launch_bounds__(256) void gcn_scatter(const float* __restrict__ x,
                                                   const float* __restrict__ ew,
                                                   const int* __restrict__ src,
                                                   const int* __restrict__ tgt,
                                                   float* __restrict__ out) {
    int tid = blockIdx.x * 256 + threadIdx.x;
    int e = tid >> 5;
    int t = tid & 31;
    if (e >= NE) return;
    int s = src[e];
    int g = tgt[e];
    float w = ew[e];
    float4 xv = reinterpret_cast<const float4*>(x)[s * 32 + t];
    float* dst = out + (size_t)g * D + (t << 2);
    atomicAdd(dst + 0, xv.x * w);
    atomicAdd(dst + 1, xv.y * w);
    atomicAdd(dst + 2, xv.z * w);
    atomicAdd(dst + 3, xv.w * w);
}

extern "C" void kernel_launch(void* const* d_in, const int* in_sizes, int n_in,
                              void* d_out, int out_size, void* d_ws, size_t ws_size,
                              hipStream_t stream) {
    const float* x   = (const float*)d_in[0];
    const float* W   = (const float*)d_in[1];
    const float* ew  = (const float*)d_in[2];
    const int*   src = (const int*)d_in[3];
    const int*   tgt = (const int*)d_in[4];
    float* out = (float*)d_out;

    if (ws_size >= WS_T2) {
        char* ws = (char*)d_ws;
        int*  counts  = (int*)(ws + OFF_COUNTS);
        int*  offsets = (int*)(ws + OFF_OFFSETS);
        int*  cursor  = (int*)(ws + OFF_CURSOR);
        int*  bsum    = (int*)(ws + OFF_BSUM);
        int*  bsumex  = (int*)(ws + OFF_BSUMEX);
        int2* pe      = (int2*)(ws + OFF_PE);

        hipMemsetAsync(counts, 0, (size_t)NN * sizeof(int), stream);
        k_hist<<<(NE + 255) / 256, 256, 0, stream>>>(tgt, counts);
        k_scan_part<<<NBLK, 256, 0, stream>>>(counts, bsum);
        k_scan_mid<<<1, 128, 0, stream>>>(bsum, bsumex, offsets);
        k_scan_final<<<NBLK, 256, 0, stream>>>(counts, bsumex, offsets, cursor);
        k_fill<<<(NE + 255) / 256, 256, 0, stream>>>(src, tgt, ew, cursor, pe);

        if (ws_size >= WS_FULL) {
            unsigned* xb = (unsigned*)(ws + OFF_XB);
            k_conv<<<(NN * 64 + 255) / 256, 256, 0, stream>>>(x, xb);
            k_gather_bf<<<(NN + 3) / 4, 256, 0, stream>>>(xb, offsets, pe, out);
        } else {
            k_gather_f32<<<(NN + 3) / 4, 256, 0, stream>>>(x, offsets, pe, out);
        }
    } else {
        hipMemsetAsync(out, 0, (size_t)out_size * sizeof(float), stream);
        gcn_scatter<<<(NE * 32 + 255) / 256, 256, 0, stream>>>(x, ew, src, tgt, out);
    }

    k_project<<<(NN + PBN - 1) / PBN, 256, 0, stream>>>(W, out);
}

// Round 9
// 261.102 us; speedup vs baseline: 2.0995x; 1.1264x over previous
//
#include <hip/hip_runtime.h>
#include <hip/hip_bf16.h>

#define NN 100000
#define NE 640000
#define D 128

#define SCAN_CHUNK 1024
#define NBLK ((NN + SCAN_CHUNK - 1) / SCAN_CHUNK)   // 98

// ---- workspace layout (bytes) ----
#define OFF_COUNTS  0u                         // NN*4
#define OFF_OFFSETS 400000u                    // (NN+1)*4, padded
#define OFF_CURSOR  800016u                    // NN*4
#define OFF_BSUM    1200016u                   // 512 B
#define OFF_BSUMEX  1200528u                   // 512 B
#define OFF_PE      1201040u                   // NE*8  (int2 packed src,w)
#define WS_T2       6321040u                   // tier-2 end
#define OFF_XB      6321040u                   // NN*64*4 (packed bf16x2 rows)
#define WS_FULL     31921040u                  // tier-1 end

typedef __attribute__((ext_vector_type(8))) short bf16x8;
typedef __attribute__((ext_vector_type(4))) float f32x4;

__device__ __forceinline__ float bflo(unsigned u) { return __uint_as_float(u << 16); }
__device__ __forceinline__ float bfhi(unsigned u) { return __uint_as_float(u & 0xffff0000u); }
__device__ __forceinline__ unsigned bfpk(float x, float y) {
    __hip_bfloat16 bx = __float2bfloat16(x), by = __float2bfloat16(y);
    return (unsigned)(*(unsigned short*)&bx) | ((unsigned)(*(unsigned short*)&by) << 16);
}

// ---------------------------------------------------------------------------
// histogram of targets
// ---------------------------------------------------------------------------
__global__ __launch_bounds__(256) void k_hist(const int* __restrict__ tgt,
                                              int* __restrict__ counts) {
    int e = blockIdx.x * 256 + threadIdx.x;
    if (e < NE) atomicAdd(&counts[tgt[e]], 1);
}

// ---------------------------------------------------------------------------
// multi-block scan (round-5 verified): partial sums -> mid scan -> final
// ---------------------------------------------------------------------------
__global__ __launch_bounds__(256) void k_scan_part(const int* __restrict__ counts,
                                                   int* __restrict__ bsum) {
    __shared__ int sd[256];
    int b = blockIdx.x, t = threadIdx.x;
    int base = b * SCAN_CHUNK + t * 4;
    int s = 0;
    #pragma unroll
    for (int k = 0; k < 4; ++k) { int i = base + k; s += (i < NN) ? counts[i] : 0; }
    sd[t] = s; __syncthreads();
    for (int off = 128; off > 0; off >>= 1) {
        if (t < off) sd[t] += sd[t + off];
        __syncthreads();
    }
    if (t == 0) bsum[b] = sd[0];
}

__global__ __launch_bounds__(128) void k_scan_mid(const int* __restrict__ bsum,
                                                  int* __restrict__ bsumex,
                                                  int* __restrict__ offsets) {
    __shared__ int sd[128];
    int t = threadIdx.x;
    int v = (t < NBLK) ? bsum[t] : 0;
    sd[t] = v; __syncthreads();
    for (int off = 1; off < 128; off <<= 1) {
        int tmp = (t >= off) ? sd[t - off] : 0;
        __syncthreads();
        sd[t] += tmp;
        __syncthreads();
    }
    if (t < NBLK) bsumex[t] = sd[t] - v;
    if (t == 0) offsets[NN] = NE;
}

__global__ __launch_bounds__(256) void k_scan_final(const int* __restrict__ counts,
                                                    const int* __restrict__ bsumex,
                                                    int* __restrict__ offsets,
                                                    int* __restrict__ cursor) {
    __shared__ int sd[256];
    int b = blockIdx.x, t = threadIdx.x;
    int base = b * SCAN_CHUNK + t * 4;
    int c[4]; int s = 0;
    #pragma unroll
    for (int k = 0; k < 4; ++k) { int i = base + k; c[k] = (i < NN) ? counts[i] : 0; s += c[k]; }
    sd[t] = s; __syncthreads();
    for (int off = 1; off < 256; off <<= 1) {
        int tmp = (t >= off) ? sd[t - off] : 0;
        __syncthreads();
        sd[t] += tmp;
        __syncthreads();
    }
    int run = sd[t] - s + bsumex[b];
    #pragma unroll
    for (int k = 0; k < 4; ++k) {
        int i = base + k;
        if (i < NN) { offsets[i] = run; cursor[i] = run; }
        run += c[k];
    }
}

// ---------------------------------------------------------------------------
// bucket edges by target, packed (src, w) -> one 8B store per edge
// ---------------------------------------------------------------------------
__global__ __launch_bounds__(256) void k_fill(const int* __restrict__ src,
                                              const int* __restrict__ tgt,
                                              const float* __restrict__ ew,
                                              int* __restrict__ cursor,
                                              int2* __restrict__ pe) {
    int e = blockIdx.x * 256 + threadIdx.x;
    if (e < NE) {
        int t = tgt[e];
        int p = atomicAdd(&cursor[t], 1);
        pe[p] = make_int2(src[e], __float_as_int(ew[e]));
    }
}

// ---------------------------------------------------------------------------
// x (fp32) -> packed bf16x2 rows (halves gather-path bytes)
// ---------------------------------------------------------------------------
__global__ __launch_bounds__(256) void k_conv(const float* __restrict__ x,
                                              unsigned* __restrict__ xb) {
    int i = blockIdx.x * 256 + threadIdx.x;      // over NN*64 packed words
    if (i < NN * 64) {
        float2 v = ((const float2*)x)[i];
        xb[i] = bfpk(v.x, v.y);
    }
}

// ---------------------------------------------------------------------------
// Pull aggregation, bf16 x: one wave per node, zero atomics, writes row once
// ---------------------------------------------------------------------------
__global__ __launch_bounds__(256) void k_gather_bf(const unsigned* __restrict__ xb,
                                                   const int* __restrict__ offsets,
                                                   const int2* __restrict__ pe,
                                                   float* __restrict__ out) {
    int wid = blockIdx.x * 4 + (threadIdx.x >> 6);
    int lane = threadIdx.x & 63;
    if (wid >= NN) return;
    int beg = offsets[wid], end = offsets[wid + 1];
    float a0 = 0.f, a1 = 0.f;
    int2 e = (beg < end) ? pe[beg] : make_int2(0, 0);
    for (int i = beg; i < end; ++i) {
        int2 en = (i + 1 < end) ? pe[i + 1] : make_int2(0, 0);   // prefetch
        unsigned v = xb[(size_t)e.x * 64 + lane];
        float w = __int_as_float(e.y);
        a0 = fmaf(bflo(v), w, a0);
        a1 = fmaf(bfhi(v), w, a1);
        e = en;
    }
    ((float2*)out)[(size_t)wid * 64 + lane] = make_float2(a0, a1);
}

// tier-2 variant: fp32 x directly (round-5 verified structure, pe-packed)
__global__ __launch_bounds__(256) void k_gather_f32(const float* __restrict__ x,
                                                    const int* __restrict__ offsets,
                                                    const int2* __restrict__ pe,
                                                    float* __restrict__ out) {
    int wid = blockIdx.x * 4 + (threadIdx.x >> 6);
    int lane = threadIdx.x & 63;
    if (wid >= NN) return;
    int beg = offsets[wid], end = offsets[wid + 1];
    const float2* x2 = (const float2*)x;
    float a0 = 0.f, a1 = 0.f;
    int2 e = (beg < end) ? pe[beg] : make_int2(0, 0);
    for (int i = beg; i < end; ++i) {
        int2 en = (i + 1 < end) ? pe[i + 1] : make_int2(0, 0);
        float2 v = x2[(size_t)e.x * 64 + lane];
        float w = __int_as_float(e.y);
        a0 = fmaf(v.x, w, a0);
        a1 = fmaf(v.y, w, a1);
        e = en;
    }
    ((float2*)out)[(size_t)wid * 64 + lane] = make_float2(a0, a1);
}

// ---------------------------------------------------------------------------
// MFMA in-place projection: io[n] <- io[n] @ W^T
// 64 rows/block, 4 waves x 16 rows. A (agg rows) and B (W, [f][k]) staged as
// bf16 in LDS, rows padded to 136 elems (272 B stride -> 2-way bank alias,
// free per m136). A- and B-frags use the SAME (lane-group,elem)->k addressing,
// so any HW k-slot permutation cancels; only M/N=lane&15 and the verified C/D
// mapping (col=lane&15, row=(lane>>4)*4+reg) matter.
// ---------------------------------------------------------------------------
#define KP 136

__global__ __launch_bounds__(256) void k_project_mfma(const float* __restrict__ W,
                                                      float* __restrict__ io) {
    __shared__ unsigned short Wb[D][KP];    // [f][k] bf16, 34816 B
    __shared__ unsigned short As[64][KP];   // [n][k] bf16, 17408 B

    const int tid = threadIdx.x;
    const long nb = (long)blockIdx.x * 64;

    // stage W -> Wb[f][k] (bf16): 4096 float4 / 256 threads
    const float4* W4 = (const float4*)W;
    #pragma unroll
    for (int it = 0; it < 16; ++it) {
        int idx = it * 256 + tid;
        int f = idx >> 5, kq = idx & 31;
        float4 v = W4[idx];
        *(uint2*)&Wb[f][kq * 4] = make_uint2(bfpk(v.x, v.y), bfpk(v.z, v.w));
    }
    // stage 64 agg rows -> As[n][k] (bf16): 2048 float4 / 256 threads
    const float4* io4 = (const float4*)io;
    #pragma unroll
    for (int it = 0; it < 8; ++it) {
        int idx = it * 256 + tid;
        int n = idx >> 5, kq = idx & 31;
        long node = nb + n;
        float4 v = (node < NN) ? io4[node * 32 + kq]
                               : make_float4(0.f, 0.f, 0.f, 0.f);
        *(uint2*)&As[n][kq * 4] = make_uint2(bfpk(v.x, v.y), bfpk(v.z, v.w));
    }
    __syncthreads();

    const int w  = tid >> 6;          // wave 0..3 -> rows w*16..w*16+15
    const int l  = tid & 63;
    const int lr = l & 15;            // M/N lane index
    const int lg = l >> 4;            // k-group
    const int r0 = w * 16;

    bf16x8 afrag[4];
    #pragma unroll
    for (int ks = 0; ks < 4; ++ks)
        afrag[ks] = *(const bf16x8*)&As[r0 + lr][ks * 32 + lg * 8];

    #pragma unroll
    for (int ct = 0; ct < 8; ++ct) {
        f32x4 acc = {0.f, 0.f, 0.f, 0.f};
        #pragma unroll
        for (int ks = 0; ks < 4; ++ks) {
            bf16x8 bfrag = *(const bf16x8*)&Wb[ct * 16 + lr][ks * 32 + lg * 8];
            acc = __builtin_amdgcn_mfma_f32_16x16x32_bf16(afrag[ks], bfrag, acc, 0, 0, 0);
        }
        #pragma unroll
        for (int r = 0; r < 4; ++r) {
            long gn = nb + r0 + lg * 4 + r;
            if (gn < NN) io[gn * D + ct * 16 + lr] = acc[r];
        }
    }
}

// ---------------------------------------------------------------------------
// tier-3 fallback: direct atomic scatter in x-space
// ---------------------------------------------------------------------------
__global__ __launch_bounds__(256) void gcn_scatter(const float* __restrict__ x,
                                                   const float* __restrict__ ew,
                                                   const int* __restrict__ src,
                                                   const int* __restrict__ tgt,
                                                   float* __restrict__ out) {
    int tid = blockIdx.x * 256 + threadIdx.x;
    int e = tid >> 5;
    int t = tid & 31;
    if (e >= NE) return;
    int s = src[e];
    int g = tgt[e];
    float w = ew[e];
    float4 xv = reinterpret_cast<const float4*>(x)[s * 32 + t];
    float* dst = out + (size_t)g * D + (t << 2);
    atomicAdd(dst + 0, xv.x * w);
    atomicAdd(dst + 1, xv.y * w);
    atomicAdd(dst + 2, xv.z * w);
    atomicAdd(dst + 3, xv.w * w);
}

extern "C" void kernel_launch(void* const* d_in, const int* in_sizes, int n_in,
                              void* d_out, int out_size, void* d_ws, size_t ws_size,
                              hipStream_t stream) {
    const float* x   = (const float*)d_in[0];
    const float* W   = (const float*)d_in[1];
    const float* ew  = (const float*)d_in[2];
    const int*   src = (const int*)d_in[3];
    const int*   tgt = (const int*)d_in[4];
    float* out = (float*)d_out;

    if (ws_size >= WS_T2) {
        char* ws = (char*)d_ws;
        int*  counts  = (int*)(ws + OFF_COUNTS);
        int*  offsets = (int*)(ws + OFF_OFFSETS);
        int*  cursor  = (int*)(ws + OFF_CURSOR);
        int*  bsum    = (int*)(ws + OFF_BSUM);
        int*  bsumex  = (int*)(ws + OFF_BSUMEX);
        int2* pe      = (int2*)(ws + OFF_PE);

        hipMemsetAsync(counts, 0, (size_t)NN * sizeof(int), stream);
        k_hist<<<(NE + 255) / 256, 256, 0, stream>>>(tgt, counts);
        k_scan_part<<<NBLK, 256, 0, stream>>>(counts, bsum);
        k_scan_mid<<<1, 128, 0, stream>>>(bsum, bsumex, offsets);
        k_scan_final<<<NBLK, 256, 0, stream>>>(counts, bsumex, offsets, cursor);
        k_fill<<<(NE + 255) / 256, 256, 0, stream>>>(src, tgt, ew, cursor, pe);

        if (ws_size >= WS_FULL) {
            unsigned* xb = (unsigned*)(ws + OFF_XB);
            k_conv<<<(NN * 64 + 255) / 256, 256, 0, stream>>>(x, xb);
            k_gather_bf<<<(NN + 3) / 4, 256, 0, stream>>>(xb, offsets, pe, out);
        } else {
            k_gather_f32<<<(NN + 3) / 4, 256, 0, stream>>>(x, offsets, pe, out);
        }
    } else {
        hipMemsetAsync(out, 0, (size_t)out_size * sizeof(float), stream);
        gcn_scatter<<<(NE * 32 + 255) / 256, 256, 0, stream>>>(x, ew, src, tgt, out);
    }

    k_project_mfma<<<(NN + 63) / 64, 256, 0, stream>>>(W, out);
}